// Round 6
// baseline (401.802 us; speedup 1.0000x reference)
//
#include <hip/hip_runtime.h>

#define TT  8
#define NN  50000
#define EE  5000
#define NZ  100000
#define DD  128
#define NTILES ((NN + 63) / 64)   // 782
#define ECAP 64                   // max hyperedge degree stored
#define NCAP 32                   // max node degree stored
#define LSTR 136                  // LDS row stride in shorts (272 B: b128-aligned, low-conflict)

typedef __attribute__((ext_vector_type(8))) short short8v;
typedef __attribute__((ext_vector_type(4))) float float4v;

__device__ __forceinline__ unsigned short f2bf(float f) {
    return __builtin_bit_cast(unsigned short, (__bf16)f);
}
__device__ __forceinline__ float bf2f(unsigned short u) {
    return (float)__builtin_bit_cast(__bf16, u);
}

// ---------------- ELL build: one pass, no scan ----------------
__global__ __launch_bounds__(256) void k_build(const int* __restrict__ pn, const int* __restrict__ pe,
                                               int* __restrict__ dvcnt, int* __restrict__ decnt,
                                               int* __restrict__ ell_e, int* __restrict__ ell_n) {
    const int t = blockIdx.x & 7;
    const int i = (blockIdx.x >> 3) * 256 + threadIdx.x;
    if (i >= NZ) return;
    int n = pn[(size_t)t * NZ + i];
    int e = pe[(size_t)t * NZ + i];
    int se = atomicAdd(&decnt[(size_t)t * EE + e], 1);
    if (se < ECAP) ell_e[((size_t)t * EE + e) * ECAP + se] = n;
    int sn = atomicAdd(&dvcnt[(size_t)t * NN + n], 1);
    if (sn < NCAP) ell_n[((size_t)t * NN + n) * NCAP + sn] = e;
}

// ---------------- degree finalize ----------------
__global__ __launch_bounds__(256) void k_fin(const int* __restrict__ dvcnt, const int* __restrict__ decnt,
                                             float* __restrict__ dvis, float* __restrict__ deinv) {
    int i = blockIdx.x * 256 + threadIdx.x;
    if (i < TT * NN) {
        int c = dvcnt[i];
        dvis[i] = (c > 0) ? rsqrtf((float)c) : 0.0f;
    } else {
        int j = i - TT * NN;
        if (j < TT * EE) {
            int c = decnt[j];
            deinv[j] = (c > 0) ? 1.0f / (float)c : 0.0f;
        }
    }
}

// ---------------- W fragment precompute (hi/lo bf16, MFMA fragment-major) ----------------
__global__ __launch_bounds__(256) void k_prepw(const float* __restrict__ W0, const float* __restrict__ W1,
                                               unsigned short* __restrict__ fragH,
                                               unsigned short* __restrict__ fragL) {
    const float* W = blockIdx.x ? W1 : W0;
    unsigned short* fh = fragH + (size_t)blockIdx.x * 16384;
    unsigned short* fl = fragL + (size_t)blockIdx.x * 16384;
    const int wave = threadIdx.x >> 6, lane = threadIdx.x & 63;
    const int l15 = lane & 15, l4 = lane >> 4;
    #pragma unroll
    for (int c = 0; c < 2; c++)
        #pragma unroll
        for (int s = 0; s < 4; s++)
            #pragma unroll
            for (int j = 0; j < 8; j++) {
                float wv = W[(size_t)(s * 32 + l4 * 8 + j) * DD + wave * 32 + c * 16 + l15];
                unsigned short h = f2bf(wv);
                int idx = (((wave * 2 + c) * 4 + s) * 64 + lane) * 8 + j;
                fh[idx] = h;
                fl[idx] = f2bf(wv - bf2f(h));
            }
}

// ---------------- shared GEMM epilogue: acc -> LDS (bias,dv,bf16) -> coalesced store ----------------
__device__ __forceinline__ void gemm_epilogue(unsigned short* Af, float4v acc[4][2],
                                              const float* __restrict__ bias,
                                              const float* __restrict__ dv, int row0,
                                              unsigned short* __restrict__ out,
                                              int wave, int lane, int l15, int l4, int tid) {
    float b2[2] = { bias[wave * 32 + l15], bias[wave * 32 + 16 + l15] };
    __syncthreads();   // all fragment reads done; LDS reusable
    #pragma unroll
    for (int r = 0; r < 4; r++) {
        int rloc = r * 16 + l4 * 4;
        if (row0 + rloc < NN) {
            float4 dv4 = *(const float4*)(dv + row0 + rloc);
            float dvv[4] = {dv4.x, dv4.y, dv4.z, dv4.w};
            #pragma unroll
            for (int c = 0; c < 2; c++)
                #pragma unroll
                for (int g = 0; g < 4; g++)
                    Af[(rloc + g) * LSTR + wave * 32 + c * 16 + l15] =
                        f2bf((acc[r][c][g] + b2[c]) * dvv[g]);
        }
    }
    __syncthreads();
    #pragma unroll
    for (int it = 0; it < 8; it++) {     // 8*256 = 2048 = 64 rows x 32 col-groups (was 4: lost rows 32-63)
        int idx = it * 256 + tid;
        int row = idx >> 5, col4 = idx & 31;
        if (row0 + row < NN) {
            unsigned u0 = *(const unsigned*)(&Af[row * LSTR + col4 * 4]);
            unsigned u1 = *(const unsigned*)(&Af[row * LSTR + col4 * 4 + 2]);
            unsigned out2[2] = {u0, u1};
            *(uint2*)(out + (size_t)(row0 + row) * DD + col4 * 4) = *(uint2*)out2;
        }
    }
}

// ---------------- GEMM layer 0: coalesced load -> LDS -> MFMA -> coalesced epilogue ----------------
__global__ __launch_bounds__(256) void k_gemm0(const float* __restrict__ x,
                                               const unsigned short* __restrict__ fragH,
                                               const unsigned short* __restrict__ fragL,
                                               const float* __restrict__ bias,
                                               const float* __restrict__ dvis,
                                               unsigned short* __restrict__ xs) {
    __shared__ unsigned short Af[64 * LSTR];
    const int t = blockIdx.x & 7;
    const int tile = blockIdx.x >> 3;
    const int row0 = tile * 64;
    const float* src = x + (size_t)t * NN * DD;
    unsigned short* out = xs + (size_t)t * NN * DD;
    const float* dv = dvis + (size_t)t * NN;
    const int tid = threadIdx.x;
    const int wave = tid >> 6, lane = tid & 63;
    const int l15 = lane & 15, l4 = lane >> 4;

    // phase 1: fully-coalesced x load + bf16 convert + LDS row-major
    #pragma unroll
    for (int it = 0; it < 8; it++) {
        int idx = it * 256 + tid;
        int row = idx >> 5, col4 = idx & 31;
        float4 a = make_float4(0.f, 0.f, 0.f, 0.f);
        if (row0 + row < NN) a = *(const float4*)(src + (size_t)(row0 + row) * DD + col4 * 4);
        unsigned u0 = (unsigned)f2bf(a.x) | ((unsigned)f2bf(a.y) << 16);
        unsigned u1 = (unsigned)f2bf(a.z) | ((unsigned)f2bf(a.w) << 16);
        *(unsigned*)(&Af[row * LSTR + col4 * 4]) = u0;
        *(unsigned*)(&Af[row * LSTR + col4 * 4 + 2]) = u1;
    }

    short8v wh[2][4], wl[2][4];
    #pragma unroll
    for (int c = 0; c < 2; c++)
        #pragma unroll
        for (int s = 0; s < 4; s++) {
            int base = (((wave * 2 + c) * 4 + s) * 64 + lane) * 8;
            wh[c][s] = *(const short8v*)(fragH + base);
            wl[c][s] = *(const short8v*)(fragL + base);
        }
    __syncthreads();

    // phase 2: fragment reads + MFMA
    float4v acc[4][2] = {};
    #pragma unroll
    for (int s = 0; s < 4; s++)
        #pragma unroll
        for (int r = 0; r < 4; r++) {
            short8v a = *(const short8v*)(&Af[(r * 16 + l15) * LSTR + s * 32 + l4 * 8]);
            #pragma unroll
            for (int c = 0; c < 2; c++) {
                acc[r][c] = __builtin_amdgcn_mfma_f32_16x16x32_bf16(a, wh[c][s], acc[r][c], 0, 0, 0);
                acc[r][c] = __builtin_amdgcn_mfma_f32_16x16x32_bf16(a, wl[c][s], acc[r][c], 0, 0, 0);
            }
        }

    gemm_epilogue(Af, acc, bias, dv, row0, out, wave, lane, l15, l4, tid);
}

// ---------------- GEMM layer 1 (A frag-major in global) + coalesced epilogue ----------------
__global__ __launch_bounds__(256) void k_gemm1(const unsigned short* __restrict__ hF,
                                               const unsigned short* __restrict__ fragH,
                                               const unsigned short* __restrict__ fragL,
                                               const float* __restrict__ bias,
                                               const float* __restrict__ dvis,
                                               unsigned short* __restrict__ xs) {
    __shared__ unsigned short Af[64 * LSTR];
    const int t = blockIdx.x & 7;
    const int tile = blockIdx.x >> 3;
    const int row0 = tile * 64;
    const unsigned short* hA = hF + (size_t)t * NTILES * 8192 + (size_t)tile * 8192;
    unsigned short* out = xs + (size_t)t * NN * DD;
    const float* dv = dvis + (size_t)t * NN;
    const int tid = threadIdx.x;
    const int wave = tid >> 6, lane = tid & 63;
    const int l15 = lane & 15, l4 = lane >> 4;

    short8v wh[2][4], wl[2][4];
    #pragma unroll
    for (int c = 0; c < 2; c++)
        #pragma unroll
        for (int s = 0; s < 4; s++) {
            int base = (((wave * 2 + c) * 4 + s) * 64 + lane) * 8;
            wh[c][s] = *(const short8v*)(fragH + base);
            wl[c][s] = *(const short8v*)(fragL + base);
        }

    float4v acc[4][2] = {};
    #pragma unroll
    for (int s = 0; s < 4; s++)
        #pragma unroll
        for (int r = 0; r < 4; r++) {
            short8v a = *(const short8v*)(hA + (size_t)((s * 4 + r) * 64 + lane) * 8);
            #pragma unroll
            for (int c = 0; c < 2; c++) {
                acc[r][c] = __builtin_amdgcn_mfma_f32_16x16x32_bf16(a, wh[c][s], acc[r][c], 0, 0, 0);
                acc[r][c] = __builtin_amdgcn_mfma_f32_16x16x32_bf16(a, wl[c][s], acc[r][c], 0, 0, 0);
            }
        }

    gemm_epilogue(Af, acc, bias, dv, row0, out, wave, lane, l15, l4, tid);
}

// ---------------- gather node->edge (16-lane group per edge, ELL + shfl broadcast) ----------------
__global__ __launch_bounds__(256) void k_gather_e(const int* __restrict__ ell_e, const int* __restrict__ decnt,
                                                  const float* __restrict__ deinv,
                                                  const unsigned short* __restrict__ xs,
                                                  unsigned short* __restrict__ ef) {
    const int t = blockIdx.x & 7;
    const int e = (blockIdx.x >> 3) * 16 + (threadIdx.x >> 4);
    const int lane16 = threadIdx.x & 15;
    if (e >= EE) return;
    const unsigned short* xsrc = xs + (size_t)t * NN * DD;
    const int* ellrow = ell_e + ((size_t)t * EE + e) * ECAP;
    int cnt = decnt[(size_t)t * EE + e];
    cnt = cnt < ECAP ? cnt : ECAP;
    float inv = deinv[(size_t)t * EE + e];
    float acc[8] = {};
    for (int b = 0; b < ECAP; b += 16) {
        if (b >= cnt) break;
        int idx = ellrow[b + lane16];
        #pragma unroll
        for (int j = 0; j < 16; j++) {
            if (b + j < cnt) {
                int n = __shfl(idx, j, 16);
                short8v v = *(const short8v*)(xsrc + (size_t)n * DD + lane16 * 8);
                #pragma unroll
                for (int k = 0; k < 8; k++) acc[k] += bf2f((unsigned short)v[k]);
            }
        }
    }
    short8v o;
    #pragma unroll
    for (int k = 0; k < 8; k++) o[k] = (short)f2bf(acc[k] * inv);
    *(short8v*)(ef + ((size_t)t * EE + e) * DD + lane16 * 8) = o;
}

// ---------------- gather edge->node, layer 0: relu(sum*dv) frag-major ----------------
__global__ __launch_bounds__(256) void k_gather_n0(const int* __restrict__ ell_n, const int* __restrict__ dvcnt,
                                                   const unsigned short* __restrict__ ef,
                                                   const float* __restrict__ dvis,
                                                   unsigned short* __restrict__ hF) {
    const int t = blockIdx.x & 7;
    const int n = (blockIdx.x >> 3) * 16 + (threadIdx.x >> 4);
    const int lane16 = threadIdx.x & 15;
    if (n >= NN) return;
    const unsigned short* esrc = ef + (size_t)t * EE * DD;
    const int* ellrow = ell_n + ((size_t)t * NN + n) * NCAP;
    int cnt = dvcnt[(size_t)t * NN + n];
    cnt = cnt < NCAP ? cnt : NCAP;
    float dvn = dvis[(size_t)t * NN + n];
    float acc[8] = {};
    int idx = ellrow[lane16];
    #pragma unroll
    for (int j = 0; j < 16; j++) {
        if (j < cnt) {
            int e = __shfl(idx, j, 16);
            short8v v = *(const short8v*)(esrc + (size_t)e * DD + lane16 * 8);
            #pragma unroll
            for (int k = 0; k < 8; k++) acc[k] += bf2f((unsigned short)v[k]);
        }
    }
    if (cnt > 16) {    // rare tail
        int idx2 = ellrow[16 + lane16];
        #pragma unroll
        for (int j = 0; j < 16; j++) {
            if (16 + j < cnt) {
                int e = __shfl(idx2, j, 16);
                short8v v = *(const short8v*)(esrc + (size_t)e * DD + lane16 * 8);
                #pragma unroll
                for (int k = 0; k < 8; k++) acc[k] += bf2f((unsigned short)v[k]);
            }
        }
    }
    // frag-major store: row=n, cols lane16*8..+7
    int tile = n >> 6, r = (n >> 4) & 3, l15n = n & 15;
    int s = lane16 >> 2, l4 = lane16 & 3;
    size_t word = (size_t)(s * 4 + r) * 64 + l4 * 16 + l15n;
    short8v o;
    #pragma unroll
    for (int k = 0; k < 8; k++) o[k] = (short)f2bf(fmaxf(acc[k] * dvn, 0.f));
    *(short8v*)(hF + (size_t)t * NTILES * 8192 + (size_t)tile * 8192 + word * 8) = o;
}

// ---------------- gather edge->node, layer 1: fused relu + mean-pool ----------------
__global__ __launch_bounds__(256) void k_gather_n1(const int* __restrict__ ell_n, const int* __restrict__ dvcnt,
                                                   const unsigned short* __restrict__ ef,
                                                   const float* __restrict__ dvis,
                                                   float* __restrict__ outp) {
    const int t = blockIdx.x & 7;
    const int nbase = (blockIdx.x >> 3) * 128 + (threadIdx.x >> 4) * 8;
    const int g = threadIdx.x >> 4;
    const int lane16 = threadIdx.x & 15;
    const unsigned short* esrc = ef + (size_t)t * EE * DD;
    float px[8] = {};
    #pragma unroll
    for (int i = 0; i < 8; i++) {
        int n = nbase + i;
        if (n < NN) {
            const int* ellrow = ell_n + ((size_t)t * NN + n) * NCAP;
            int cnt = dvcnt[(size_t)t * NN + n];
            cnt = cnt < NCAP ? cnt : NCAP;
            float dvn = dvis[(size_t)t * NN + n];
            float acc[8] = {};
            int idx = ellrow[lane16];
            #pragma unroll
            for (int j = 0; j < 16; j++) {
                if (j < cnt) {
                    int e = __shfl(idx, j, 16);
                    short8v v = *(const short8v*)(esrc + (size_t)e * DD + lane16 * 8);
                    #pragma unroll
                    for (int k = 0; k < 8; k++) acc[k] += bf2f((unsigned short)v[k]);
                }
            }
            if (cnt > 16) {
                int idx2 = ellrow[16 + lane16];
                #pragma unroll
                for (int j = 0; j < 16; j++) {
                    if (16 + j < cnt) {
                        int e = __shfl(idx2, j, 16);
                        short8v v = *(const short8v*)(esrc + (size_t)e * DD + lane16 * 8);
                        #pragma unroll
                        for (int k = 0; k < 8; k++) acc[k] += bf2f((unsigned short)v[k]);
                    }
                }
            }
            #pragma unroll
            for (int k = 0; k < 8; k++) px[k] += fmaxf(acc[k] * dvn, 0.f);
        }
    }
    __shared__ float sp[16][128];
    #pragma unroll
    for (int k = 0; k < 8; k++) sp[g][lane16 * 8 + k] = px[k];
    __syncthreads();
    if (threadIdx.x < 128) {
        float ssum = 0.f;
        #pragma unroll
        for (int gg = 0; gg < 16; gg++) ssum += sp[gg][threadIdx.x];
        atomicAdd(outp + (size_t)t * DD + threadIdx.x, ssum * (1.0f / (float)NN));
    }
}

extern "C" void kernel_launch(void* const* d_in, const int* in_sizes, int n_in,
                              void* d_out, int out_size, void* d_ws, size_t ws_size,
                              hipStream_t stream) {
    const float* x  = (const float*)d_in[0];
    const float* W0 = (const float*)d_in[1];
    const float* b0 = (const float*)d_in[2];
    const float* W1 = (const float*)d_in[3];
    const float* b1 = (const float*)d_in[4];
    const int*   pn = (const int*)d_in[5];
    const int*   pe = (const int*)d_in[6];
    float* out = (float*)d_out;

    char* p = (char*)d_ws;
    auto alloc = [&](size_t bytes) -> char* {
        char* r = p;
        p += (bytes + 255) / 256 * 256;
        return r;
    };
    float* dvis  = (float*)alloc((size_t)TT * NN * 4);
    float* deinv = (float*)alloc((size_t)TT * EE * 4);
    int*   dvcnt = (int*)alloc((size_t)TT * (NN + EE) * 4);   // dvcnt then decnt, contiguous
    int*   decnt = dvcnt + (size_t)TT * NN;
    int*   ell_e = (int*)alloc((size_t)TT * EE * ECAP * 4);   // 10.2 MB
    int*   ell_n = (int*)alloc((size_t)TT * NN * NCAP * 4);   // 51.2 MB
    unsigned short* wfragH = (unsigned short*)alloc(2 * 16384 * 2);
    unsigned short* wfragL = (unsigned short*)alloc(2 * 16384 * 2);
    unsigned short* xs = (unsigned short*)alloc((size_t)TT * NN * DD * 2);       // 102.4 MB
    unsigned short* ef = (unsigned short*)alloc((size_t)TT * EE * DD * 2);       // 10.2 MB
    unsigned short* hF = (unsigned short*)alloc((size_t)TT * NTILES * 8192 * 2); // 102.5 MB

    hipMemsetAsync(dvcnt, 0, (size_t)TT * (NN + EE) * 4, stream);
    hipMemsetAsync(d_out, 0, (size_t)out_size * 4, stream);

    k_prepw<<<2, 256, 0, stream>>>(W0, W1, wfragH, wfragL);
    k_build<<<((NZ + 255) / 256) * 8, 256, 0, stream>>>(pn, pe, dvcnt, decnt, ell_e, ell_n);
    k_fin<<<(TT * (NN + EE) + 255) / 256, 256, 0, stream>>>(dvcnt, decnt, dvis, deinv);

    // layer 0
    k_gemm0<<<NTILES * 8, 256, 0, stream>>>(x, wfragH, wfragL, b0, dvis, xs);
    k_gather_e<<<((EE + 15) / 16) * 8, 256, 0, stream>>>(ell_e, decnt, deinv, xs, ef);
    k_gather_n0<<<((NN + 15) / 16) * 8, 256, 0, stream>>>(ell_n, dvcnt, ef, dvis, hF);
    // layer 1
    k_gemm1<<<NTILES * 8, 256, 0, stream>>>(hF, wfragH + 16384, wfragL + 16384, b1, dvis, xs);
    k_gather_e<<<((EE + 15) / 16) * 8, 256, 0, stream>>>(ell_e, decnt, deinv, xs, ef);
    k_gather_n1<<<((NN + 127) / 128) * 8, 256, 0, stream>>>(ell_n, dvcnt, ef, dvis, out);
}

// Round 7
// 383.491 us; speedup vs baseline: 1.0477x; 1.0477x over previous
//
#include <hip/hip_runtime.h>

#define TT  8
#define NN  50000
#define EE  5000
#define NZ  100000
#define DD  128
#define NTILES ((NN + 63) / 64)   // 782
#define ECAP 64                   // max hyperedge degree stored
#define NCAP 32                   // max node degree stored
#define LSTR 136                  // LDS row stride in shorts (272 B)
#define TPB 4                     // tiles per persistent block

typedef __attribute__((ext_vector_type(8))) short short8v;
typedef __attribute__((ext_vector_type(4))) float float4v;

__device__ __forceinline__ unsigned short f2bf(float f) {
    return __builtin_bit_cast(unsigned short, (__bf16)f);
}
__device__ __forceinline__ float bf2f(unsigned short u) {
    return (float)__builtin_bit_cast(__bf16, u);
}

// ---------------- ELL build: one pass, no scan ----------------
__global__ __launch_bounds__(256) void k_build(const int* __restrict__ pn, const int* __restrict__ pe,
                                               int* __restrict__ dvcnt, int* __restrict__ decnt,
                                               int* __restrict__ ell_e, int* __restrict__ ell_n) {
    const int t = blockIdx.x & 7;
    const int i = (blockIdx.x >> 3) * 256 + threadIdx.x;
    if (i >= NZ) return;
    int n = pn[(size_t)t * NZ + i];
    int e = pe[(size_t)t * NZ + i];
    int se = atomicAdd(&decnt[(size_t)t * EE + e], 1);
    if (se < ECAP) ell_e[((size_t)t * EE + e) * ECAP + se] = n;
    int sn = atomicAdd(&dvcnt[(size_t)t * NN + n], 1);
    if (sn < NCAP) ell_n[((size_t)t * NN + n) * NCAP + sn] = e;
}

// ---------------- degree finalize ----------------
__global__ __launch_bounds__(256) void k_fin(const int* __restrict__ dvcnt, const int* __restrict__ decnt,
                                             float* __restrict__ dvis, float* __restrict__ deinv) {
    int i = blockIdx.x * 256 + threadIdx.x;
    if (i < TT * NN) {
        int c = dvcnt[i];
        dvis[i] = (c > 0) ? rsqrtf((float)c) : 0.0f;
    } else {
        int j = i - TT * NN;
        if (j < TT * EE) {
            int c = decnt[j];
            deinv[j] = (c > 0) ? 1.0f / (float)c : 0.0f;
        }
    }
}

// ---------------- W fragment precompute (hi/lo bf16, MFMA fragment-major) ----------------
__global__ __launch_bounds__(256) void k_prepw(const float* __restrict__ W0, const float* __restrict__ W1,
                                               unsigned short* __restrict__ fragH,
                                               unsigned short* __restrict__ fragL) {
    const float* W = blockIdx.x ? W1 : W0;
    unsigned short* fh = fragH + (size_t)blockIdx.x * 16384;
    unsigned short* fl = fragL + (size_t)blockIdx.x * 16384;
    const int wave = threadIdx.x >> 6, lane = threadIdx.x & 63;
    const int l15 = lane & 15, l4 = lane >> 4;
    #pragma unroll
    for (int c = 0; c < 2; c++)
        #pragma unroll
        for (int s = 0; s < 4; s++)
            #pragma unroll
            for (int j = 0; j < 8; j++) {
                float wv = W[(size_t)(s * 32 + l4 * 8 + j) * DD + wave * 32 + c * 16 + l15];
                unsigned short h = f2bf(wv);
                int idx = (((wave * 2 + c) * 4 + s) * 64 + lane) * 8 + j;
                fh[idx] = h;
                fl[idx] = f2bf(wv - bf2f(h));
            }
}

// ---------------- persistent pipelined GEMM ----------------
// LAYER 0: A = x (fp32, row-major) -> convert+stage.  LAYER 1: A = hF (bf16, frag-major).
// Each block: 4 tiles, double-buffered A-LDS, prefetch tile i+1 under MFMA of tile i.
template <int LAYER>
__global__ __launch_bounds__(256) void k_gemmp(const float* __restrict__ x,
                                               const unsigned short* __restrict__ hF,
                                               const unsigned short* __restrict__ fragH,
                                               const unsigned short* __restrict__ fragL,
                                               const float* __restrict__ bias,
                                               const float* __restrict__ dvis,
                                               unsigned short* __restrict__ xs) {
    __shared__ unsigned short A_lds[2][64 * LSTR];
    __shared__ unsigned short E_lds[64 * LSTR];
    const int t = blockIdx.x & 7;
    const int chunk = blockIdx.x >> 3;
    const int tile0 = chunk * TPB;
    int ntile = NTILES - tile0;
    if (ntile <= 0) return;
    if (ntile > TPB) ntile = TPB;

    const float* src = x + (size_t)t * NN * DD;
    const unsigned short* hT = hF + (size_t)t * NTILES * 8192;
    unsigned short* outp = xs + (size_t)t * NN * DD;
    const float* dv = dvis + (size_t)t * NN;
    const int tid = threadIdx.x;
    const int wave = tid >> 6, lane = tid & 63;
    const int l15 = lane & 15, l4 = lane >> 4;

    // W fragments: once per block
    short8v wh[2][4], wl[2][4];
    #pragma unroll
    for (int c = 0; c < 2; c++)
        #pragma unroll
        for (int s = 0; s < 4; s++) {
            int base = (((wave * 2 + c) * 4 + s) * 64 + lane) * 8;
            wh[c][s] = *(const short8v*)(fragH + base);
            wl[c][s] = *(const short8v*)(fragL + base);
        }
    const float b2[2] = { bias[wave * 32 + l15], bias[wave * 32 + 16 + l15] };

    float4 pf0[8];
    short8v pf1[4];

    auto PREFETCH = [&](int tile) {
        if (LAYER == 0) {
            #pragma unroll
            for (int it = 0; it < 8; it++) {
                int idx = it * 256 + tid;
                int row = tile * 64 + (idx >> 5), col4 = idx & 31;
                pf0[it] = (row < NN) ? *(const float4*)(src + (size_t)row * DD + col4 * 4)
                                     : make_float4(0.f, 0.f, 0.f, 0.f);
            }
        } else {
            #pragma unroll
            for (int q = 0; q < 4; q++)
                pf1[q] = *(const short8v*)(hT + (size_t)tile * 8192 + (size_t)(q * 256 + tid) * 8);
        }
    };
    auto STAGE = [&](int buf) {
        if (LAYER == 0) {
            #pragma unroll
            for (int it = 0; it < 8; it++) {
                int idx = it * 256 + tid;
                int row = idx >> 5, col4 = idx & 31;
                float4 a = pf0[it];
                unsigned u0 = (unsigned)f2bf(a.x) | ((unsigned)f2bf(a.y) << 16);
                unsigned u1 = (unsigned)f2bf(a.z) | ((unsigned)f2bf(a.w) << 16);
                *(uint2*)(&A_lds[buf][row * LSTR + col4 * 4]) = make_uint2(u0, u1);
            }
        } else {
            #pragma unroll
            for (int q = 0; q < 4; q++)
                *(short8v*)(&A_lds[buf][(size_t)(q * 256 + tid) * 8]) = pf1[q];
        }
    };

    PREFETCH(tile0);
    for (int i = 0; i < ntile; i++) {
        const int tile = tile0 + i;
        const int row0 = tile * 64;
        const int buf = i & 1;

        STAGE(buf);
        __syncthreads();
        if (i + 1 < ntile) PREFETCH(tile0 + i + 1);   // in flight under MFMA + epilogue

        float4v acc[4][2] = {};
        #pragma unroll
        for (int s = 0; s < 4; s++)
            #pragma unroll
            for (int r = 0; r < 4; r++) {
                short8v a;
                if (LAYER == 0)
                    a = *(const short8v*)(&A_lds[buf][(r * 16 + l15) * LSTR + s * 32 + l4 * 8]);
                else
                    a = *(const short8v*)(&A_lds[buf][(size_t)((s * 4 + r) * 64 + lane) * 8]);
                #pragma unroll
                for (int c = 0; c < 2; c++) {
                    acc[r][c] = __builtin_amdgcn_mfma_f32_16x16x32_bf16(a, wh[c][s], acc[r][c], 0, 0, 0);
                    acc[r][c] = __builtin_amdgcn_mfma_f32_16x16x32_bf16(a, wl[c][s], acc[r][c], 0, 0, 0);
                }
            }

        // epilogue: acc -> E_lds (bias, dv, bf16) -> coalesced store
        #pragma unroll
        for (int r = 0; r < 4; r++) {
            int rloc = r * 16 + l4 * 4;
            if (row0 + rloc < NN) {
                float4 dv4 = *(const float4*)(dv + row0 + rloc);
                float dvv[4] = {dv4.x, dv4.y, dv4.z, dv4.w};
                #pragma unroll
                for (int c = 0; c < 2; c++)
                    #pragma unroll
                    for (int g = 0; g < 4; g++)
                        E_lds[(rloc + g) * LSTR + wave * 32 + c * 16 + l15] =
                            f2bf((acc[r][c][g] + b2[c]) * dvv[g]);
            }
        }
        __syncthreads();
        #pragma unroll
        for (int it = 0; it < 8; it++) {
            int idx = it * 256 + tid;
            int row = idx >> 5, col4 = idx & 31;
            if (row0 + row < NN) {
                unsigned u0 = *(const unsigned*)(&E_lds[row * LSTR + col4 * 4]);
                unsigned u1 = *(const unsigned*)(&E_lds[row * LSTR + col4 * 4 + 2]);
                unsigned o2[2] = {u0, u1};
                *(uint2*)(outp + (size_t)(row0 + row) * DD + col4 * 4) = *(uint2*)o2;
            }
        }
        // next iteration's STAGE writes A_lds[buf^1]; barrier at its top bounds wave drift.
    }
}

// ---------------- gather node->edge (16-lane group per edge, ELL + shfl broadcast) ----------------
__global__ __launch_bounds__(256) void k_gather_e(const int* __restrict__ ell_e, const int* __restrict__ decnt,
                                                  const float* __restrict__ deinv,
                                                  const unsigned short* __restrict__ xs,
                                                  unsigned short* __restrict__ ef) {
    const int t = blockIdx.x & 7;
    const int e = (blockIdx.x >> 3) * 16 + (threadIdx.x >> 4);
    const int lane16 = threadIdx.x & 15;
    if (e >= EE) return;
    const unsigned short* xsrc = xs + (size_t)t * NN * DD;
    const int* ellrow = ell_e + ((size_t)t * EE + e) * ECAP;
    int cnt = decnt[(size_t)t * EE + e];
    cnt = cnt < ECAP ? cnt : ECAP;
    float inv = deinv[(size_t)t * EE + e];
    float acc[8] = {};
    for (int b = 0; b < ECAP; b += 16) {
        if (b >= cnt) break;
        int idx = ellrow[b + lane16];
        #pragma unroll
        for (int j = 0; j < 16; j++) {
            if (b + j < cnt) {
                int n = __shfl(idx, j, 16);
                short8v v = *(const short8v*)(xsrc + (size_t)n * DD + lane16 * 8);
                #pragma unroll
                for (int k = 0; k < 8; k++) acc[k] += bf2f((unsigned short)v[k]);
            }
        }
    }
    short8v o;
    #pragma unroll
    for (int k = 0; k < 8; k++) o[k] = (short)f2bf(acc[k] * inv);
    *(short8v*)(ef + ((size_t)t * EE + e) * DD + lane16 * 8) = o;
}

// ---------------- gather edge->node, layer 0: relu(sum*dv) frag-major ----------------
__global__ __launch_bounds__(256) void k_gather_n0(const int* __restrict__ ell_n, const int* __restrict__ dvcnt,
                                                   const unsigned short* __restrict__ ef,
                                                   const float* __restrict__ dvis,
                                                   unsigned short* __restrict__ hF) {
    const int t = blockIdx.x & 7;
    const int n = (blockIdx.x >> 3) * 16 + (threadIdx.x >> 4);
    const int lane16 = threadIdx.x & 15;
    if (n >= NN) return;
    const unsigned short* esrc = ef + (size_t)t * EE * DD;
    const int* ellrow = ell_n + ((size_t)t * NN + n) * NCAP;
    int cnt = dvcnt[(size_t)t * NN + n];
    cnt = cnt < NCAP ? cnt : NCAP;
    float dvn = dvis[(size_t)t * NN + n];
    float acc[8] = {};
    int idx = ellrow[lane16];
    #pragma unroll
    for (int j = 0; j < 16; j++) {
        if (j < cnt) {
            int e = __shfl(idx, j, 16);
            short8v v = *(const short8v*)(esrc + (size_t)e * DD + lane16 * 8);
            #pragma unroll
            for (int k = 0; k < 8; k++) acc[k] += bf2f((unsigned short)v[k]);
        }
    }
    if (cnt > 16) {
        int idx2 = ellrow[16 + lane16];
        #pragma unroll
        for (int j = 0; j < 16; j++) {
            if (16 + j < cnt) {
                int e = __shfl(idx2, j, 16);
                short8v v = *(const short8v*)(esrc + (size_t)e * DD + lane16 * 8);
                #pragma unroll
                for (int k = 0; k < 8; k++) acc[k] += bf2f((unsigned short)v[k]);
            }
        }
    }
    int tile = n >> 6, r = (n >> 4) & 3, l15n = n & 15;
    int s = lane16 >> 2, l4 = lane16 & 3;
    size_t word = (size_t)(s * 4 + r) * 64 + l4 * 16 + l15n;
    short8v o;
    #pragma unroll
    for (int k = 0; k < 8; k++) o[k] = (short)f2bf(fmaxf(acc[k] * dvn, 0.f));
    *(short8v*)(hF + (size_t)t * NTILES * 8192 + (size_t)tile * 8192 + word * 8) = o;
}

// ---------------- gather edge->node, layer 1: fused relu + mean-pool ----------------
__global__ __launch_bounds__(256) void k_gather_n1(const int* __restrict__ ell_n, const int* __restrict__ dvcnt,
                                                   const unsigned short* __restrict__ ef,
                                                   const float* __restrict__ dvis,
                                                   float* __restrict__ outp) {
    const int t = blockIdx.x & 7;
    const int nbase = (blockIdx.x >> 3) * 128 + (threadIdx.x >> 4) * 8;
    const int g = threadIdx.x >> 4;
    const int lane16 = threadIdx.x & 15;
    const unsigned short* esrc = ef + (size_t)t * EE * DD;
    float px[8] = {};
    #pragma unroll
    for (int i = 0; i < 8; i++) {
        int n = nbase + i;
        if (n < NN) {
            const int* ellrow = ell_n + ((size_t)t * NN + n) * NCAP;
            int cnt = dvcnt[(size_t)t * NN + n];
            cnt = cnt < NCAP ? cnt : NCAP;
            float dvn = dvis[(size_t)t * NN + n];
            float acc[8] = {};
            int idx = ellrow[lane16];
            #pragma unroll
            for (int j = 0; j < 16; j++) {
                if (j < cnt) {
                    int e = __shfl(idx, j, 16);
                    short8v v = *(const short8v*)(esrc + (size_t)e * DD + lane16 * 8);
                    #pragma unroll
                    for (int k = 0; k < 8; k++) acc[k] += bf2f((unsigned short)v[k]);
                }
            }
            if (cnt > 16) {
                int idx2 = ellrow[16 + lane16];
                #pragma unroll
                for (int j = 0; j < 16; j++) {
                    if (16 + j < cnt) {
                        int e = __shfl(idx2, j, 16);
                        short8v v = *(const short8v*)(esrc + (size_t)e * DD + lane16 * 8);
                        #pragma unroll
                        for (int k = 0; k < 8; k++) acc[k] += bf2f((unsigned short)v[k]);
                    }
                }
            }
            #pragma unroll
            for (int k = 0; k < 8; k++) px[k] += fmaxf(acc[k] * dvn, 0.f);
        }
    }
    __shared__ float sp[16][128];
    #pragma unroll
    for (int k = 0; k < 8; k++) sp[g][lane16 * 8 + k] = px[k];
    __syncthreads();
    if (threadIdx.x < 128) {
        float ssum = 0.f;
        #pragma unroll
        for (int gg = 0; gg < 16; gg++) ssum += sp[gg][threadIdx.x];
        atomicAdd(outp + (size_t)t * DD + threadIdx.x, ssum * (1.0f / (float)NN));
    }
}

extern "C" void kernel_launch(void* const* d_in, const int* in_sizes, int n_in,
                              void* d_out, int out_size, void* d_ws, size_t ws_size,
                              hipStream_t stream) {
    const float* x  = (const float*)d_in[0];
    const float* W0 = (const float*)d_in[1];
    const float* b0 = (const float*)d_in[2];
    const float* W1 = (const float*)d_in[3];
    const float* b1 = (const float*)d_in[4];
    const int*   pn = (const int*)d_in[5];
    const int*   pe = (const int*)d_in[6];
    float* out = (float*)d_out;

    char* p = (char*)d_ws;
    auto alloc = [&](size_t bytes) -> char* {
        char* r = p;
        p += (bytes + 255) / 256 * 256;
        return r;
    };
    float* dvis  = (float*)alloc((size_t)TT * NN * 4);
    float* deinv = (float*)alloc((size_t)TT * EE * 4);
    int*   dvcnt = (int*)alloc((size_t)TT * (NN + EE) * 4);
    int*   decnt = dvcnt + (size_t)TT * NN;
    int*   ell_e = (int*)alloc((size_t)TT * EE * ECAP * 4);
    int*   ell_n = (int*)alloc((size_t)TT * NN * NCAP * 4);
    unsigned short* wfragH = (unsigned short*)alloc(2 * 16384 * 2);
    unsigned short* wfragL = (unsigned short*)alloc(2 * 16384 * 2);
    unsigned short* xs = (unsigned short*)alloc((size_t)TT * NN * DD * 2);
    unsigned short* ef = (unsigned short*)alloc((size_t)TT * EE * DD * 2);
    unsigned short* hF = (unsigned short*)alloc((size_t)TT * NTILES * 8192 * 2);

    hipMemsetAsync(dvcnt, 0, (size_t)TT * (NN + EE) * 4, stream);
    hipMemsetAsync(d_out, 0, (size_t)out_size * 4, stream);

    k_prepw<<<2, 256, 0, stream>>>(W0, W1, wfragH, wfragL);
    k_build<<<((NZ + 255) / 256) * 8, 256, 0, stream>>>(pn, pe, dvcnt, decnt, ell_e, ell_n);
    k_fin<<<(TT * (NN + EE) + 255) / 256, 256, 0, stream>>>(dvcnt, decnt, dvis, deinv);

    const int GG = ((NTILES + TPB - 1) / TPB) * 8;   // 196*8 = 1568 persistent blocks

    // layer 0
    k_gemmp<0><<<GG, 256, 0, stream>>>(x, hF, wfragH, wfragL, b0, dvis, xs);
    k_gather_e<<<((EE + 15) / 16) * 8, 256, 0, stream>>>(ell_e, decnt, deinv, xs, ef);
    k_gather_n0<<<((NN + 15) / 16) * 8, 256, 0, stream>>>(ell_n, dvcnt, ef, dvis, hF);
    // layer 1
    k_gemmp<1><<<GG, 256, 0, stream>>>(x, hF, wfragH + 16384, wfragL + 16384, b1, dvis, xs);
    k_gather_e<<<((EE + 15) / 16) * 8, 256, 0, stream>>>(ell_e, decnt, deinv, xs, ef);
    k_gather_n1<<<((NN + 127) / 128) * 8, 256, 0, stream>>>(ell_n, dvcnt, ef, dvis, out);
}

// Round 8
// 313.249 us; speedup vs baseline: 1.2827x; 1.2242x over previous
//
#include <hip/hip_runtime.h>

#define TT  8
#define NN  50000
#define EE  5000
#define NZ  100000
#define DD  128
#define ETILES ((EE + 63) / 64)   // 79
#define ECAP 64                   // max hyperedge degree stored
#define NCAP 32                   // max node degree stored
#define LSTR 136                  // LDS row stride in shorts (272 B)

typedef __attribute__((ext_vector_type(8))) short short8v;
typedef __attribute__((ext_vector_type(4))) float float4v;

__device__ __forceinline__ unsigned short f2bf(float f) {
    return __builtin_bit_cast(unsigned short, (__bf16)f);
}
__device__ __forceinline__ float bf2f(unsigned short u) {
    return (float)__builtin_bit_cast(__bf16, u);
}

// ---------------- ELL build: one pass ----------------
__global__ __launch_bounds__(256) void k_build(const int* __restrict__ pn, const int* __restrict__ pe,
                                               int* __restrict__ dvcnt, int* __restrict__ decnt,
                                               int* __restrict__ ell_e, int* __restrict__ ell_n) {
    const int t = blockIdx.x & 7;
    const int i = (blockIdx.x >> 3) * 256 + threadIdx.x;
    if (i >= NZ) return;
    int n = pn[(size_t)t * NZ + i];
    int e = pe[(size_t)t * NZ + i];
    int se_ = atomicAdd(&decnt[(size_t)t * EE + e], 1);
    if (se_ < ECAP) ell_e[((size_t)t * EE + e) * ECAP + se_] = n;
    int sn = atomicAdd(&dvcnt[(size_t)t * NN + n], 1);
    if (sn < NCAP) ell_n[((size_t)t * NN + n) * NCAP + sn] = e;
}

// ---------------- degree finalize ----------------
__global__ __launch_bounds__(256) void k_fin(const int* __restrict__ dvcnt, const int* __restrict__ decnt,
                                             float* __restrict__ dvis, float* __restrict__ deinv) {
    int i = blockIdx.x * 256 + threadIdx.x;
    if (i < TT * NN) {
        int c = dvcnt[i];
        dvis[i] = (c > 0) ? rsqrtf((float)c) : 0.0f;
    } else {
        int j = i - TT * NN;
        if (j < TT * EE) {
            int c = decnt[j];
            deinv[j] = (c > 0) ? 1.0f / (float)c : 0.0f;
        }
    }
}

// ---------------- W fragment precompute (hi/lo bf16, MFMA fragment-major) ----------------
__global__ __launch_bounds__(256) void k_prepw(const float* __restrict__ W0, const float* __restrict__ W1,
                                               unsigned short* __restrict__ fragH,
                                               unsigned short* __restrict__ fragL) {
    const float* W = blockIdx.x ? W1 : W0;
    unsigned short* fh = fragH + (size_t)blockIdx.x * 16384;
    unsigned short* fl = fragL + (size_t)blockIdx.x * 16384;
    const int wave = threadIdx.x >> 6, lane = threadIdx.x & 63;
    const int l15 = lane & 15, l4 = lane >> 4;
    #pragma unroll
    for (int c = 0; c < 2; c++)
        #pragma unroll
        for (int s = 0; s < 4; s++)
            #pragma unroll
            for (int j = 0; j < 8; j++) {
                float wv = W[(size_t)(s * 32 + l4 * 8 + j) * DD + wave * 32 + c * 16 + l15];
                unsigned short h = f2bf(wv);
                int idx = (((wave * 2 + c) * 4 + s) * 64 + lane) * 8 + j;
                fh[idx] = h;
                fl[idx] = f2bf(wv - bf2f(h));
            }
}

// ---------------- gather_e0: g[e] = sum dvis[n]*x_n (fp32), se[e] = sum dvis[n] ----------------
__global__ __launch_bounds__(256) void k_gather_e0(const int* __restrict__ ell_e, const int* __restrict__ decnt,
                                                   const float* __restrict__ dvis, const float* __restrict__ x,
                                                   float* __restrict__ g, float* __restrict__ se) {
    const int t = blockIdx.x & 7;
    const int e = (blockIdx.x >> 3) * 16 + (threadIdx.x >> 4);
    const int lane16 = threadIdx.x & 15;
    if (e >= EE) return;
    const float* xsrc = x + (size_t)t * NN * DD;
    const float* dvs = dvis + (size_t)t * NN;
    const int* ellrow = ell_e + ((size_t)t * EE + e) * ECAP;
    int cnt = decnt[(size_t)t * EE + e];
    cnt = cnt < ECAP ? cnt : ECAP;
    float acc[8] = {};
    float sacc = 0.f;
    for (int b = 0; b < ECAP; b += 16) {
        if (b >= cnt) break;
        int valid = (b + lane16 < cnt);
        int idx = valid ? ellrow[b + lane16] : 0;
        float dvl = valid ? dvs[idx] : 0.f;
        #pragma unroll
        for (int j = 0; j < 16; j++) {
            if (b + j < cnt) {
                int n = __shfl(idx, j, 16);
                float dvn = __shfl(dvl, j, 16);
                float4 v0 = *(const float4*)(xsrc + (size_t)n * DD + lane16 * 8);
                float4 v1 = *(const float4*)(xsrc + (size_t)n * DD + lane16 * 8 + 4);
                acc[0] += dvn * v0.x; acc[1] += dvn * v0.y; acc[2] += dvn * v0.z; acc[3] += dvn * v0.w;
                acc[4] += dvn * v1.x; acc[5] += dvn * v1.y; acc[6] += dvn * v1.z; acc[7] += dvn * v1.w;
                sacc += dvn;
            }
        }
    }
    float* gout = g + ((size_t)t * EE + e) * DD;
    *(float4*)(gout + lane16 * 8)     = make_float4(acc[0], acc[1], acc[2], acc[3]);
    *(float4*)(gout + lane16 * 8 + 4) = make_float4(acc[4], acc[5], acc[6], acc[7]);
    if (lane16 == 0) se[(size_t)t * EE + e] = sacc;
}

// ---------------- gather_e1: g2[e] = sum dvis[n]*h_n (h bf16) ----------------
__global__ __launch_bounds__(256) void k_gather_e1(const int* __restrict__ ell_e, const int* __restrict__ decnt,
                                                   const float* __restrict__ dvis,
                                                   const unsigned short* __restrict__ h,
                                                   float* __restrict__ g) {
    const int t = blockIdx.x & 7;
    const int e = (blockIdx.x >> 3) * 16 + (threadIdx.x >> 4);
    const int lane16 = threadIdx.x & 15;
    if (e >= EE) return;
    const unsigned short* hsrc = h + (size_t)t * NN * DD;
    const float* dvs = dvis + (size_t)t * NN;
    const int* ellrow = ell_e + ((size_t)t * EE + e) * ECAP;
    int cnt = decnt[(size_t)t * EE + e];
    cnt = cnt < ECAP ? cnt : ECAP;
    float acc[8] = {};
    for (int b = 0; b < ECAP; b += 16) {
        if (b >= cnt) break;
        int valid = (b + lane16 < cnt);
        int idx = valid ? ellrow[b + lane16] : 0;
        float dvl = valid ? dvs[idx] : 0.f;
        #pragma unroll
        for (int j = 0; j < 16; j++) {
            if (b + j < cnt) {
                int n = __shfl(idx, j, 16);
                float dvn = __shfl(dvl, j, 16);
                short8v v = *(const short8v*)(hsrc + (size_t)n * DD + lane16 * 8);
                #pragma unroll
                for (int k = 0; k < 8; k++) acc[k] += dvn * bf2f((unsigned short)v[k]);
            }
        }
    }
    float* gout = g + ((size_t)t * EE + e) * DD;
    *(float4*)(gout + lane16 * 8)     = make_float4(acc[0], acc[1], acc[2], acc[3]);
    *(float4*)(gout + lane16 * 8 + 4) = make_float4(acc[4], acc[5], acc[6], acc[7]);
}

// ---------------- E-row GEMM: ef[e] = deinv[e]*(g[e] @ W) + deinv[e]*se[e]*b ----------------
// A = g (fp32, E x 128) hi/lo split in LDS; 3-term MFMA (R2-verified accuracy).
__global__ __launch_bounds__(256) void k_gemmE(const float* __restrict__ g,
                                               const float* __restrict__ se,
                                               const float* __restrict__ deinv,
                                               const unsigned short* __restrict__ fragH,
                                               const unsigned short* __restrict__ fragL,
                                               const float* __restrict__ bias,
                                               unsigned short* __restrict__ ef) {
    __shared__ unsigned short Ah[64 * LSTR];
    __shared__ unsigned short Al[64 * LSTR];
    __shared__ unsigned short E_lds[64 * LSTR];
    const int t = blockIdx.x & 7;
    const int tile = blockIdx.x >> 3;
    const int row0 = tile * 64;
    const float* gsrc = g + (size_t)t * EE * DD;
    const float* sesrc = se + (size_t)t * EE;
    const float* desrc = deinv + (size_t)t * EE;
    unsigned short* outp = ef + (size_t)t * EE * DD;
    const int tid = threadIdx.x;
    const int wave = tid >> 6, lane = tid & 63;
    const int l15 = lane & 15, l4 = lane >> 4;

    // stage A hi/lo (coalesced fp32 loads)
    #pragma unroll
    for (int it = 0; it < 8; it++) {
        int idx = it * 256 + tid;
        int row = idx >> 5, col4 = idx & 31;
        float4 a = make_float4(0.f, 0.f, 0.f, 0.f);
        if (row0 + row < EE) a = *(const float4*)(gsrc + (size_t)(row0 + row) * DD + col4 * 4);
        unsigned short hx = f2bf(a.x), hy = f2bf(a.y), hz = f2bf(a.z), hw = f2bf(a.w);
        *(uint2*)(&Ah[row * LSTR + col4 * 4]) = make_uint2(
            (unsigned)hx | ((unsigned)hy << 16), (unsigned)hz | ((unsigned)hw << 16));
        *(uint2*)(&Al[row * LSTR + col4 * 4]) = make_uint2(
            (unsigned)f2bf(a.x - bf2f(hx)) | ((unsigned)f2bf(a.y - bf2f(hy)) << 16),
            (unsigned)f2bf(a.z - bf2f(hz)) | ((unsigned)f2bf(a.w - bf2f(hw)) << 16));
    }

    short8v wh[2][4], wl[2][4];
    #pragma unroll
    for (int c = 0; c < 2; c++)
        #pragma unroll
        for (int s = 0; s < 4; s++) {
            int base = (((wave * 2 + c) * 4 + s) * 64 + lane) * 8;
            wh[c][s] = *(const short8v*)(fragH + base);
            wl[c][s] = *(const short8v*)(fragL + base);
        }
    __syncthreads();

    float4v acc[4][2] = {};
    #pragma unroll
    for (int s = 0; s < 4; s++)
        #pragma unroll
        for (int r = 0; r < 4; r++) {
            short8v ah = *(const short8v*)(&Ah[(r * 16 + l15) * LSTR + s * 32 + l4 * 8]);
            short8v al = *(const short8v*)(&Al[(r * 16 + l15) * LSTR + s * 32 + l4 * 8]);
            #pragma unroll
            for (int c = 0; c < 2; c++) {
                acc[r][c] = __builtin_amdgcn_mfma_f32_16x16x32_bf16(ah, wh[c][s], acc[r][c], 0, 0, 0);
                acc[r][c] = __builtin_amdgcn_mfma_f32_16x16x32_bf16(al, wh[c][s], acc[r][c], 0, 0, 0);
                acc[r][c] = __builtin_amdgcn_mfma_f32_16x16x32_bf16(ah, wl[c][s], acc[r][c], 0, 0, 0);
            }
        }

    float b2[2] = { bias[wave * 32 + l15], bias[wave * 32 + 16 + l15] };
    __syncthreads();
    #pragma unroll
    for (int r = 0; r < 4; r++) {
        int rloc = r * 16 + l4 * 4;
        if (row0 + rloc < EE) {   // EE % 4 == 0 -> all 4 regs valid when base < EE
            float4 de4 = *(const float4*)(desrc + row0 + rloc);
            float4 se4 = *(const float4*)(sesrc + row0 + rloc);
            float dev[4] = {de4.x, de4.y, de4.z, de4.w};
            float sev[4] = {se4.x, se4.y, se4.z, se4.w};
            #pragma unroll
            for (int c = 0; c < 2; c++)
                #pragma unroll
                for (int q = 0; q < 4; q++)
                    E_lds[(rloc + q) * LSTR + wave * 32 + c * 16 + l15] =
                        f2bf(dev[q] * (acc[r][c][q] + sev[q] * b2[c]));
        }
    }
    __syncthreads();
    #pragma unroll
    for (int it = 0; it < 8; it++) {
        int idx = it * 256 + tid;
        int row = idx >> 5, col4 = idx & 31;
        if (row0 + row < EE) {
            unsigned u0 = *(const unsigned*)(&E_lds[row * LSTR + col4 * 4]);
            unsigned u1 = *(const unsigned*)(&E_lds[row * LSTR + col4 * 4 + 2]);
            unsigned o2[2] = {u0, u1};
            *(uint2*)(outp + (size_t)(row0 + row) * DD + col4 * 4) = *(uint2*)o2;
        }
    }
}

// ---------------- gather_n0: h_n = relu(dv_n * sum ef[e]) -> bf16 row-major ----------------
__global__ __launch_bounds__(256) void k_gather_n0(const int* __restrict__ ell_n, const int* __restrict__ dvcnt,
                                                   const unsigned short* __restrict__ ef,
                                                   const float* __restrict__ dvis,
                                                   unsigned short* __restrict__ h) {
    const int t = blockIdx.x & 7;
    const int n = (blockIdx.x >> 3) * 16 + (threadIdx.x >> 4);
    const int lane16 = threadIdx.x & 15;
    if (n >= NN) return;
    const unsigned short* esrc = ef + (size_t)t * EE * DD;
    const int* ellrow = ell_n + ((size_t)t * NN + n) * NCAP;
    int cnt = dvcnt[(size_t)t * NN + n];
    cnt = cnt < NCAP ? cnt : NCAP;
    float dvn = dvis[(size_t)t * NN + n];
    float acc[8] = {};
    int idx = ellrow[lane16];
    #pragma unroll
    for (int j = 0; j < 16; j++) {
        if (j < cnt) {
            int e = __shfl(idx, j, 16);
            short8v v = *(const short8v*)(esrc + (size_t)e * DD + lane16 * 8);
            #pragma unroll
            for (int k = 0; k < 8; k++) acc[k] += bf2f((unsigned short)v[k]);
        }
    }
    if (cnt > 16) {
        int idx2 = ellrow[16 + lane16];
        #pragma unroll
        for (int j = 0; j < 16; j++) {
            if (16 + j < cnt) {
                int e = __shfl(idx2, j, 16);
                short8v v = *(const short8v*)(esrc + (size_t)e * DD + lane16 * 8);
                #pragma unroll
                for (int k = 0; k < 8; k++) acc[k] += bf2f((unsigned short)v[k]);
            }
        }
    }
    short8v o;
    #pragma unroll
    for (int k = 0; k < 8; k++) o[k] = (short)f2bf(fmaxf(acc[k] * dvn, 0.f));
    *(short8v*)(h + (size_t)t * NN * DD + (size_t)n * DD + lane16 * 8) = o;
}

// ---------------- gather_n1: fused relu + mean-pool ----------------
__global__ __launch_bounds__(256) void k_gather_n1(const int* __restrict__ ell_n, const int* __restrict__ dvcnt,
                                                   const unsigned short* __restrict__ ef,
                                                   const float* __restrict__ dvis,
                                                   float* __restrict__ outp) {
    const int t = blockIdx.x & 7;
    const int nbase = (blockIdx.x >> 3) * 128 + (threadIdx.x >> 4) * 8;
    const int gg_ = threadIdx.x >> 4;
    const int lane16 = threadIdx.x & 15;
    const unsigned short* esrc = ef + (size_t)t * EE * DD;
    float px[8] = {};
    #pragma unroll
    for (int i = 0; i < 8; i++) {
        int n = nbase + i;
        if (n < NN) {
            const int* ellrow = ell_n + ((size_t)t * NN + n) * NCAP;
            int cnt = dvcnt[(size_t)t * NN + n];
            cnt = cnt < NCAP ? cnt : NCAP;
            float dvn = dvis[(size_t)t * NN + n];
            float acc[8] = {};
            int idx = ellrow[lane16];
            #pragma unroll
            for (int j = 0; j < 16; j++) {
                if (j < cnt) {
                    int e = __shfl(idx, j, 16);
                    short8v v = *(const short8v*)(esrc + (size_t)e * DD + lane16 * 8);
                    #pragma unroll
                    for (int k = 0; k < 8; k++) acc[k] += bf2f((unsigned short)v[k]);
                }
            }
            if (cnt > 16) {
                int idx2 = ellrow[16 + lane16];
                #pragma unroll
                for (int j = 0; j < 16; j++) {
                    if (16 + j < cnt) {
                        int e = __shfl(idx2, j, 16);
                        short8v v = *(const short8v*)(esrc + (size_t)e * DD + lane16 * 8);
                        #pragma unroll
                        for (int k = 0; k < 8; k++) acc[k] += bf2f((unsigned short)v[k]);
                    }
                }
            }
            #pragma unroll
            for (int k = 0; k < 8; k++) px[k] += fmaxf(acc[k] * dvn, 0.f);
        }
    }
    __shared__ float sp[16][128];
    #pragma unroll
    for (int k = 0; k < 8; k++) sp[gg_][lane16 * 8 + k] = px[k];
    __syncthreads();
    if (threadIdx.x < 128) {
        float ssum = 0.f;
        #pragma unroll
        for (int q = 0; q < 16; q++) ssum += sp[q][threadIdx.x];
        atomicAdd(outp + (size_t)t * DD + threadIdx.x, ssum * (1.0f / (float)NN));
    }
}

extern "C" void kernel_launch(void* const* d_in, const int* in_sizes, int n_in,
                              void* d_out, int out_size, void* d_ws, size_t ws_size,
                              hipStream_t stream) {
    const float* x  = (const float*)d_in[0];
    const float* W0 = (const float*)d_in[1];
    const float* b0 = (const float*)d_in[2];
    const float* W1 = (const float*)d_in[3];
    const float* b1 = (const float*)d_in[4];
    const int*   pn = (const int*)d_in[5];
    const int*   pe = (const int*)d_in[6];
    float* out = (float*)d_out;

    char* p = (char*)d_ws;
    auto alloc = [&](size_t bytes) -> char* {
        char* r = p;
        p += (bytes + 255) / 256 * 256;
        return r;
    };
    float* dvis  = (float*)alloc((size_t)TT * NN * 4);
    float* deinv = (float*)alloc((size_t)TT * EE * 4);
    int*   dvcnt = (int*)alloc((size_t)TT * (NN + EE) * 4);   // dvcnt then decnt
    int*   decnt = dvcnt + (size_t)TT * NN;
    int*   ell_e = (int*)alloc((size_t)TT * EE * ECAP * 4);   // 10.2 MB
    int*   ell_n = (int*)alloc((size_t)TT * NN * NCAP * 4);   // 51.2 MB
    unsigned short* wfragH = (unsigned short*)alloc(2 * 16384 * 2);
    unsigned short* wfragL = (unsigned short*)alloc(2 * 16384 * 2);
    float* gbuf = (float*)alloc((size_t)TT * EE * DD * 4);    // 20.5 MB (g / g2)
    float* sebuf = (float*)alloc((size_t)TT * EE * 4);
    unsigned short* ef = (unsigned short*)alloc((size_t)TT * EE * DD * 2);  // 10.2 MB (ef / ef2)
    unsigned short* h  = (unsigned short*)alloc((size_t)TT * NN * DD * 2);  // 102.4 MB

    hipMemsetAsync(dvcnt, 0, (size_t)TT * (NN + EE) * 4, stream);
    hipMemsetAsync(d_out, 0, (size_t)out_size * 4, stream);

    k_prepw<<<2, 256, 0, stream>>>(W0, W1, wfragH, wfragL);
    k_build<<<((NZ + 255) / 256) * 8, 256, 0, stream>>>(pn, pe, dvcnt, decnt, ell_e, ell_n);
    k_fin<<<(TT * (NN + EE) + 255) / 256, 256, 0, stream>>>(dvcnt, decnt, dvis, deinv);

    const dim3 ge(((EE + 15) / 16) * 8), gn(((NN + 15) / 16) * 8);

    // layer 0: gather-then-GEMM (commuted)
    k_gather_e0<<<ge, 256, 0, stream>>>(ell_e, decnt, dvis, x, gbuf, sebuf);
    k_gemmE<<<ETILES * 8, 256, 0, stream>>>(gbuf, sebuf, deinv, wfragH, wfragL, b0, ef);
    k_gather_n0<<<gn, 256, 0, stream>>>(ell_n, dvcnt, ef, dvis, h);
    // layer 1
    k_gather_e1<<<ge, 256, 0, stream>>>(ell_e, decnt, dvis, h, gbuf);
    k_gemmE<<<ETILES * 8, 256, 0, stream>>>(gbuf, sebuf, deinv, wfragH + 16384, wfragL + 16384, b1, ef);
    k_gather_n1<<<((NN + 127) / 128) * 8, 256, 0, stream>>>(ell_n, dvcnt, ef, dvis, out);
}